// Round 1
// 542.386 us; speedup vs baseline: 1.0072x; 1.0072x over previous
//
#include <hip/hip_runtime.h>

// Problem constants
constexpr int H = 128, W = 128;
constexpr int IMG = H * W;        // 16384
constexpr int STRIP = 32;         // rows per block
constexpr int STRIPS = H / STRIP; // 4

__device__ __forceinline__ float max3f(float a, float b, float c) {
    return fmaxf(fmaxf(a, b), c);  // -> v_max3_f32
}
// hw transcendentals: v_exp_f32 = 2^x, v_log_f32 = log2(x)
__device__ __forceinline__ float exp2_hw(float x) { return __builtin_amdgcn_exp2f(x); }
__device__ __forceinline__ float log2_hw(float x) { return __builtin_amdgcn_logf(x); }
__device__ __forceinline__ float rcp_hw(float x)  { return __builtin_amdgcn_rcpf(x); }

// One block = one 32-row strip of one 128x128 image.
// Stages 34 landmark rows in LDS with row-clamp (replicate padding == -inf
// padding under a max filter). Each thread: 16 elements via float4.
//
// Loss math restructured: both branches are alpha*log2(1+2^beta)+gamma, so we
// select beta BEFORE the transcendentals and share exp2/log2(1+E):
//   lo = 9.70406*log2(1 + 2^(asl*log2 d))
//   hi = A*(d-0.5) + 9.70406*log2(1 + 2^(-asl)),  A = 28*asl*E*rcp(1+E)
// -> 4 trans ops + fast rcp per element (was 6 trans + precise div).
//
// Halo columns: vL/vR vertical maxes come from neighbor lanes via shuffle
// (they are the neighbor's v3/v0) instead of 8-way-conflicted scalar LDS
// reads; only the 2 row-boundary lanes per wave need a clamp fixup.
__global__ __launch_bounds__(256, 8) void awing_partial(
    const float* __restrict__ pred,
    const float* __restrict__ lmk,
    float* __restrict__ part)
{
    __shared__ __align__(16) float s[(STRIP + 2) * W];  // 34*128 floats = 17 KB
    __shared__ float wsum[4];

    const int tid  = threadIdx.x;
    const int img  = blockIdx.x >> 2;   // STRIPS == 4
    const int st   = blockIdx.x & 3;
    const int row0 = st * STRIP;
    const float* li = lmk  + (size_t)img * IMG;
    const float* pi = pred + (size_t)img * IMG;

    // Stage 34 rows (row0-1 .. row0+32) as float4, coalesced, row-clamped.
    for (int s4 = tid; s4 < (STRIP + 2) * (W / 4); s4 += 256) {
        int lr = s4 >> 5;          // lds row 0..33
        int c4 = s4 & 31;          // float4 column
        int gr = row0 - 1 + lr;    // global row
        gr = min(max(gr, 0), H - 1);
        ((float4*)s)[s4] = ((const float4*)li)[gr * (W / 4) + c4];
    }
    __syncthreads();

    const bool leftEdge  = (tid & 31) == 0;   // c == 0
    const bool rightEdge = (tid & 31) == 31;  // c == 124

    float acc = 0.0f;
#pragma unroll
    for (int it = 0; it < 4; ++it) {
        int e  = it * 1024 + tid * 4;   // local element 0..4095
        int rl = e >> 7;                // local row 0..31
        int c  = e & 127;               // col, multiple of 4

        float4 p4 = ((const float4*)pi)[(row0 + rl) * 32 + (c >> 2)];

        int b0 = rl * W + c;            // lds row rl == global row-1
        float4 a4 = *(const float4*)&s[b0];
        float4 b4 = *(const float4*)&s[b0 + W];      // center row (landmark vals)
        float4 d4 = *(const float4*)&s[b0 + 2 * W];

        // vertical 3-max per column; halo columns via neighbor-lane shuffle
        float v0 = max3f(a4.x, b4.x, d4.x);
        float v1 = max3f(a4.y, b4.y, d4.y);
        float v2 = max3f(a4.z, b4.z, d4.z);
        float v3 = max3f(a4.w, b4.w, d4.w);
        float vL = __shfl_up(v3, 1, 64);
        float vR = __shfl_down(v0, 1, 64);
        vL = leftEdge  ? v0 : vL;   // replicate-clamp == -inf pad under max
        vR = rightEdge ? v3 : vR;

        float mm[4] = { max3f(vL, v0, v1), max3f(v0, v1, v2),
                        max3f(v1, v2, v3), max3f(v2, v3, vR) };
        float yy[4] = { b4.x, b4.y, b4.z, b4.w };
        float pp[4] = { p4.x, p4.y, p4.z, p4.w };

#pragma unroll
        for (int j = 0; j < 4; ++j) {
            float y    = yy[j];
            float d    = fabsf(pp[j] - y);
            float asl  = 2.1f - y;                 // in (1.1, 2.1]
            bool  lo   = d < 0.5f;
            // shared-form loss: alpha*log2(1+2^beta) + gamma
            float L    = log2_hw(d);               // d==0 -> -inf -> E=0 (ok)
            float beta = lo ? asl * L : -asl;
            float E    = exp2_hw(beta);
            float S    = 1.0f + E;
            float G    = log2_hw(S);
            float A    = 28.0f * asl * E * rcp_hw(S);  // T2 = 2*T1 exact
            float Asel = lo ? 0.0f : A;
            float lossv = fmaf(Asel, d - 0.5f, 9.704060527839234f * G);
            // weight: rne(z)>=25.6 <=> z>=25.5 (round-half-even), z = 255*max3x3
            float wgt  = (mm[j] * 255.0f >= 25.5f) ? 11.0f : 1.0f;
            acc = fmaf(lossv, wgt, acc);
        }
    }

    // block reduction: wave64 shuffle then 4 partials in LDS
#pragma unroll
    for (int off = 32; off > 0; off >>= 1) acc += __shfl_down(acc, off, 64);
    if ((tid & 63) == 0) wsum[tid >> 6] = acc;
    __syncthreads();
    if (tid == 0) part[blockIdx.x] = (wsum[0] + wsum[1]) + (wsum[2] + wsum[3]);
}

__global__ void final_reduce(const float* __restrict__ part, int n,
                             float* __restrict__ out, double inv_total)
{
    __shared__ double sd[4];
    int tid = threadIdx.x;
    double a = 0.0;
    for (int i = tid; i < n; i += 256) a += (double)part[i];
#pragma unroll
    for (int off = 32; off > 0; off >>= 1) a += __shfl_down(a, off, 64);
    if ((tid & 63) == 0) sd[tid >> 6] = a;
    __syncthreads();
    if (tid == 0) out[0] = (float)((sd[0] + sd[1] + sd[2] + sd[3]) * inv_total);
}

extern "C" void kernel_launch(void* const* d_in, const int* in_sizes, int n_in,
                              void* d_out, int out_size, void* d_ws, size_t ws_size,
                              hipStream_t stream)
{
    const float* pred = (const float*)d_in[0];
    const float* lmk  = (const float*)d_in[1];
    float* part = (float*)d_ws;           // 17408 floats = 68 KB scratch
    int total   = in_sizes[0];            // 71303168
    int nimg    = total / IMG;            // 4352
    int nblocks = nimg * STRIPS;          // 17408

    awing_partial<<<nblocks, 256, 0, stream>>>(pred, lmk, part);
    final_reduce<<<1, 256, 0, stream>>>(part, nblocks, (float*)d_out,
                                        1.0 / (double)total);
}

// Round 2
// 541.140 us; speedup vs baseline: 1.0095x; 1.0023x over previous
//
#include <hip/hip_runtime.h>

// Problem constants
constexpr int H = 128, W = 128;
constexpr int IMG = H * W;        // 16384
constexpr int STRIP = 32;         // rows per 32-lane unit
constexpr int STRIPS = H / STRIP; // 4
constexpr int UNITS_PER_BLOCK = 8; // 256 threads = 8 x 32-lane units

__device__ __forceinline__ float max3f(float a, float b, float c) {
    return fmaxf(fmaxf(a, b), c);  // -> v_max3_f32
}
// hw transcendentals: v_exp_f32 = 2^x, v_log_f32 = log2(x)
__device__ __forceinline__ float exp2_hw(float x) { return __builtin_amdgcn_exp2f(x); }
__device__ __forceinline__ float log2_hw(float x) { return __builtin_amdgcn_logf(x); }
__device__ __forceinline__ float rcp_hw(float x)  { return __builtin_amdgcn_rcpf(x); }

// One 32-lane group = one (image, 32-row strip). No LDS tile, no barrier:
// rolling 3-row landmark window in registers (float4/lane = 4 columns),
// horizontal halo via 2 width-32 shuffles, depth-1 prefetch of the next
// lmk/pred rows. Row-replicate clamp == -inf pad of lax.reduce_window
// under a max filter.
//
// Loss math (verified absmax=0 in round 1): both branches share the form
// alpha*log2(1+2^beta)+gamma -> select beta BEFORE the transcendentals:
//   lo = 9.70406*log2(1 + 2^(asl*log2 d))
//   hi = A*(d-0.5) + 9.70406*log2(1 + 2^(-asl)), A = 28*asl*E*rcp(1+E)
__global__ __launch_bounds__(256, 8) void awing_partial(
    const float* __restrict__ pred,
    const float* __restrict__ lmk,
    float* __restrict__ part)
{
    __shared__ float wsum[4];

    const int tid  = threadIdx.x;
    const int lane = tid & 31;                            // float4 column
    const int unit = blockIdx.x * UNITS_PER_BLOCK + (tid >> 5);
    const int img  = unit >> 2;                           // STRIPS == 4
    const int st   = unit & 3;
    const int row0 = st * STRIP;
    const float4* l4 = (const float4*)(lmk  + (size_t)img * IMG);
    const float4* p4 = (const float4*)(pred + (size_t)img * IMG);
    // row r, this lane -> l4[r*32 + lane]

    const bool le = (lane == 0), re = (lane == 31);

    // rolling window: A=l[r-1], B=l[r], C=l[r+1]; D is the prefetch target
    float4 A = l4[max(row0 - 1, 0) * 32 + lane];
    float4 B = l4[row0 * 32 + lane];
    float4 C = l4[(row0 + 1) * 32 + lane];
    float4 D;
    float4 P = p4[row0 * 32 + lane];

    float acc = 0.0f;

#define ROW_STEP(A_, B_, C_, D_, r_)                                         \
    {                                                                        \
        D_ = l4[min((r_) + 2, H - 1) * 32 + lane];   /* prefetch l[r+2] */   \
        float4 Pn = p4[min((r_) + 1, H - 1) * 32 + lane]; /* p[r+1] */       \
        float v0 = max3f(A_.x, B_.x, C_.x);                                  \
        float v1 = max3f(A_.y, B_.y, C_.y);                                  \
        float v2 = max3f(A_.z, B_.z, C_.z);                                  \
        float v3 = max3f(A_.w, B_.w, C_.w);                                  \
        float vL = __shfl_up(v3, 1, 32);                                     \
        float vR = __shfl_down(v0, 1, 32);                                   \
        vL = le ? v0 : vL;   /* replicate-clamp == -inf pad under max */     \
        vR = re ? v3 : vR;                                                   \
        float mm[4] = { max3f(vL, v0, v1), max3f(v0, v1, v2),                \
                        max3f(v1, v2, v3), max3f(v2, v3, vR) };              \
        float yy[4] = { B_.x, B_.y, B_.z, B_.w };                            \
        float pp[4] = { P.x, P.y, P.z, P.w };                                \
        _Pragma("unroll")                                                    \
        for (int j = 0; j < 4; ++j) {                                        \
            float y    = yy[j];                                              \
            float d    = fabsf(pp[j] - y);                                   \
            float asl  = 2.1f - y;              /* in (1.1, 2.1] */          \
            bool  lo   = d < 0.5f;                                           \
            float L    = log2_hw(d);            /* d==0 -> -inf -> E=0 ok */ \
            float beta = lo ? asl * L : -asl;                                \
            float E    = exp2_hw(beta);                                      \
            float S    = 1.0f + E;                                           \
            float G    = log2_hw(S);                                         \
            float Aw   = 28.0f * asl * E * rcp_hw(S);  /* T2 = 2*T1 */       \
            float Asel = lo ? 0.0f : Aw;                                     \
            float lossv = fmaf(Asel, d - 0.5f, 9.704060527839234f * G);      \
            /* rne(z)>=25.6 <=> z>=25.5 (round-half-even), z=255*max3x3 */   \
            float wgt  = (mm[j] * 255.0f >= 25.5f) ? 11.0f : 1.0f;           \
            acc = fmaf(lossv, wgt, acc);                                     \
        }                                                                    \
        P = Pn;                                                              \
    }

    // 32 rows, 4-register rotation, fully unrolled groups of 4
    for (int r = row0; r < row0 + STRIP; r += 4) {
        ROW_STEP(A, B, C, D, r)
        ROW_STEP(B, C, D, A, r + 1)
        ROW_STEP(C, D, A, B, r + 2)
        ROW_STEP(D, A, B, C, r + 3)
    }
#undef ROW_STEP

    // block reduction: wave64 shuffle then 4 partials in LDS
#pragma unroll
    for (int off = 32; off > 0; off >>= 1) acc += __shfl_down(acc, off, 64);
    if ((tid & 63) == 0) wsum[tid >> 6] = acc;
    __syncthreads();
    if (tid == 0) part[blockIdx.x] = (wsum[0] + wsum[1]) + (wsum[2] + wsum[3]);
}

__global__ void final_reduce(const float* __restrict__ part, int n,
                             float* __restrict__ out, double inv_total)
{
    __shared__ double sd[4];
    int tid = threadIdx.x;
    double a = 0.0;
    for (int i = tid; i < n; i += 256) a += (double)part[i];
#pragma unroll
    for (int off = 32; off > 0; off >>= 1) a += __shfl_down(a, off, 64);
    if ((tid & 63) == 0) sd[tid >> 6] = a;
    __syncthreads();
    if (tid == 0) out[0] = (float)((sd[0] + sd[1] + sd[2] + sd[3]) * inv_total);
}

extern "C" void kernel_launch(void* const* d_in, const int* in_sizes, int n_in,
                              void* d_out, int out_size, void* d_ws, size_t ws_size,
                              hipStream_t stream)
{
    const float* pred = (const float*)d_in[0];
    const float* lmk  = (const float*)d_in[1];
    float* part = (float*)d_ws;
    int total   = in_sizes[0];            // 71303168
    int nimg    = total / IMG;            // 4352
    int nunits  = nimg * STRIPS;          // 17408
    int nblocks = nunits / UNITS_PER_BLOCK; // 2176

    awing_partial<<<nblocks, 256, 0, stream>>>(pred, lmk, part);
    final_reduce<<<1, 256, 0, stream>>>(part, nblocks, (float*)d_out,
                                        1.0 / (double)total);
}